// Round 8
// baseline (140.378 us; speedup 1.0000x reference)
//
#include <hip/hip_runtime.h>
#include <hip/hip_bf16.h>

#define TT   256
#define BB   8
#define SS   256
#define DD   512
#define C2LOG2E 2.8853900817779268f   // 2*log2(e)
#define LOG2E   1.4426950408889634f

typedef __attribute__((ext_vector_type(8))) short bf16x8;
typedef __attribute__((ext_vector_type(4))) float f32x4;

__device__ __forceinline__ unsigned short f2bf(float f) {
    unsigned u = __builtin_bit_cast(unsigned, f);
    u += 0x7FFFu + ((u >> 16) & 1u);
    return (unsigned short)(u >> 16);
}
__device__ __forceinline__ float bf2f(unsigned short h) {
    unsigned u = (unsigned)h << 16;
    return __builtin_bit_cast(float, u);
}

// ---------------------------------------------------------------------------
// MFMA projection GEMMs, split-bf16 (hi/lo). 512 blocks, XCD-pinned.
//   z=0: eq [b*256+t][k] = exp2(c*qp)   row-major
//   z=1: ekT[b][k][s]    = exp2(c*kp)   column-major (transposed via LDS)
// ---------------------------------------------------------------------------
#define LDK 72
__global__ __launch_bounds__(256) void gemm_mfma(const float* __restrict__ query,
                                                 const float* __restrict__ keys,
                                                 const float* __restrict__ Wa,
                                                 float* __restrict__ eq,
                                                 float* __restrict__ ekT) {
    __shared__ __align__(16) unsigned char smem[4 * 64 * LDK * 2];  // 36 KB
    unsigned short* sAh = (unsigned short*)smem;
    unsigned short* sAl = sAh + 64 * LDK;
    unsigned short* sBh = sAl + 64 * LDK;
    unsigned short* sBl = sBh + 64 * LDK;
    float* Cst = (float*)smem;                // reused for z=1 transpose

    const int idx = blockIdx.x;
    const int b   = idx & 7;
    const int r2  = idx >> 3;
    const int q   = r2 & 3;
    const int x   = (r2 >> 2) & 7;
    const int z   = r2 >> 5;
    const bool isQ = (z == 0);

    const float* A  = isQ ? query : keys;
    const int strideR = isQ ? BB * DD : DD;
    const int strideB = isQ ? DD : SS * DD;
    const float* Bsrc = Wa + (isQ ? 0 : DD);

    const int tileN = x * 64;
    const int tid = threadIdx.x;
    const int rb  = tid >> 4;
    const int c4  = tid & 15;

    const float* arow0 = A + (size_t)b * strideB + (size_t)(q * 64) * strideR;
    const float* brow0 = Bsrc + (size_t)tileN * (2 * DD);

    float4 av[4], bv[4];
    #pragma unroll
    for (int i = 0; i < 4; ++i) {
        av[i] = *(const float4*)(arow0 + (size_t)(rb + 16*i) * strideR + c4 * 4);
        bv[i] = *(const float4*)(brow0 + (size_t)(rb + 16*i) * (2*DD) + c4 * 4);
    }

    const int w    = tid >> 6;
    const int lane = tid & 63;
    const int wm   = (w >> 1) * 32;
    const int wn   = (w & 1) * 32;
    const int r16  = lane & 15;
    const int k8   = (lane >> 4) * 8;

    f32x4 acc[2][2] = {};

    for (int kb = 0; kb < DD; kb += 64) {
        __syncthreads();
        #pragma unroll
        for (int i = 0; i < 4; ++i) {
            const int row = rb + 16 * i;
            float4 a = av[i], bq = bv[i];
            ushort4 ah, al, bh, bl;
            ah.x = f2bf(a.x); al.x = f2bf(a.x - bf2f(ah.x));
            ah.y = f2bf(a.y); al.y = f2bf(a.y - bf2f(ah.y));
            ah.z = f2bf(a.z); al.z = f2bf(a.z - bf2f(ah.z));
            ah.w = f2bf(a.w); al.w = f2bf(a.w - bf2f(ah.w));
            bh.x = f2bf(bq.x); bl.x = f2bf(bq.x - bf2f(bh.x));
            bh.y = f2bf(bq.y); bl.y = f2bf(bq.y - bf2f(bh.y));
            bh.z = f2bf(bq.z); bl.z = f2bf(bq.z - bf2f(bh.z));
            bh.w = f2bf(bq.w); bl.w = f2bf(bq.w - bf2f(bh.w));
            *(ushort4*)(sAh + row * LDK + c4 * 4) = ah;
            *(ushort4*)(sAl + row * LDK + c4 * 4) = al;
            *(ushort4*)(sBh + row * LDK + c4 * 4) = bh;
            *(ushort4*)(sBl + row * LDK + c4 * 4) = bl;
        }
        __syncthreads();
        if (kb + 64 < DD) {
            #pragma unroll
            for (int i = 0; i < 4; ++i) {
                av[i] = *(const float4*)(arow0 + (size_t)(rb + 16*i) * strideR + kb + 64 + c4 * 4);
                bv[i] = *(const float4*)(brow0 + (size_t)(rb + 16*i) * (2*DD) + kb + 64 + c4 * 4);
            }
        }
        #pragma unroll
        for (int ks = 0; ks < 2; ++ks) {
            const int ko = ks * 32 + k8;
            bf16x8 a_h[2], a_l[2], b_h[2], b_l[2];
            #pragma unroll
            for (int mt = 0; mt < 2; ++mt) {
                a_h[mt] = *(const bf16x8*)(sAh + (wm + mt*16 + r16) * LDK + ko);
                a_l[mt] = *(const bf16x8*)(sAl + (wm + mt*16 + r16) * LDK + ko);
            }
            #pragma unroll
            for (int nt = 0; nt < 2; ++nt) {
                b_h[nt] = *(const bf16x8*)(sBh + (wn + nt*16 + r16) * LDK + ko);
                b_l[nt] = *(const bf16x8*)(sBl + (wn + nt*16 + r16) * LDK + ko);
            }
            #pragma unroll
            for (int mt = 0; mt < 2; ++mt)
                #pragma unroll
                for (int nt = 0; nt < 2; ++nt) {
                    acc[mt][nt] = __builtin_amdgcn_mfma_f32_16x16x32_bf16(a_h[mt], b_h[nt], acc[mt][nt], 0, 0, 0);
                    acc[mt][nt] = __builtin_amdgcn_mfma_f32_16x16x32_bf16(a_h[mt], b_l[nt], acc[mt][nt], 0, 0, 0);
                    acc[mt][nt] = __builtin_amdgcn_mfma_f32_16x16x32_bf16(a_l[mt], b_h[nt], acc[mt][nt], 0, 0, 0);
                }
        }
    }

    const int crow = (lane >> 4) * 4;
    if (isQ) {
        #pragma unroll
        for (int mt = 0; mt < 2; ++mt)
            #pragma unroll
            for (int nt = 0; nt < 2; ++nt)
                #pragma unroll
                for (int i = 0; i < 4; ++i) {
                    const int m = b * 256 + q * 64 + wm + mt*16 + crow + i;
                    const int n = tileN + wn + nt*16 + r16;
                    eq[(size_t)m * DD + n] = __builtin_amdgcn_exp2f(acc[mt][nt][i] * C2LOG2E);
                }
    } else {
        __syncthreads();
        #pragma unroll
        for (int mt = 0; mt < 2; ++mt)
            #pragma unroll
            for (int nt = 0; nt < 2; ++nt)
                #pragma unroll
                for (int i = 0; i < 4; ++i)
                    Cst[(wm + mt*16 + crow + i) * 69 + wn + nt*16 + r16] =
                        __builtin_amdgcn_exp2f(acc[mt][nt][i] * C2LOG2E);
        __syncthreads();
        const int n  = tid & 63;       // local k
        const int sg = tid >> 6;       // s-quarter of the 64-row tile
        float* dstp = ekT + (size_t)b * DD * SS + (size_t)(tileN + n) * SS + q * 64 + sg * 16;
        #pragma unroll
        for (int j4 = 0; j4 < 4; ++j4) {
            float4 o;
            o.x = Cst[(sg*16 + j4*4 + 0) * 69 + n];
            o.y = Cst[(sg*16 + j4*4 + 1) * 69 + n];
            o.z = Cst[(sg*16 + j4*4 + 2) * 69 + n];
            o.w = Cst[(sg*16 + j4*4 + 3) * 69 + n];
            *(float4*)(dstp + j4 * 4) = o;
        }
    }
}

// ---------------------------------------------------------------------------
// Fused attention. 512 blocks x 1024 threads (16 waves), XCD-pinned.
// Wave w = (th = w>>3, c = w&7): computes t-rows {t0+2th, t0+2th+1} over
// k-chunk [64c, 64c+64), lane owns s = 4*lane..4*lane+3 (coalesced dwordx4).
// 4-way k-batched rcp (13 VALU + 1 rcp per 4 k); weight = -2*sum (+const
// dropped by softmax). 8 waves/SIMD to hide L2 latency.
// ---------------------------------------------------------------------------
__global__ __launch_bounds__(1024, 8) void attn_fused(const float* __restrict__ eq,
                                                      const float* __restrict__ ekT,
                                                      const float* __restrict__ va,
                                                      const float* __restrict__ values,
                                                      float* __restrict__ out) {
    __shared__ __align__(16) float wacc[8][4][256];  // 32 KB [kchunk][t][s]
    __shared__ __align__(16) float w_s[4][256];      // 4 KB
    __shared__ float red_m[4][4];                    // [sq][t]
    __shared__ float red_s[4][4];

    const int tid  = threadIdx.x;
    const int lane = tid & 63;
    const int w    = tid >> 6;          // 0..15
    const int c    = w & 7;             // k-chunk
    const int th   = w >> 3;            // t-half
    const int idx  = blockIdx.x;
    const int b    = idx & 7;           // XCD pin
    const int t0   = (idx >> 3) * 4;
    const int k0   = c * 64;

    const float* ekp = ekT + ((size_t)b * DD + k0) * SS + lane * 4;
    const float4* qpa = (const float4*)(eq + (size_t)(b * TT + t0 + 2*th + 0) * DD + k0);
    const float4* qpb = (const float4*)(eq + (size_t)(b * TT + t0 + 2*th + 1) * DD + k0);
    const float4* vap = (const float4*)(va + k0);

    float aA0=0,aA1=0,aA2=0,aA3=0, aB0=0,aB1=0,aB2=0,aB3=0;

    #pragma unroll 4
    for (int kb = 0; kb < 64; kb += 4) {
        float4 ek0 = *(const float4*)(ekp + 0 * SS);
        float4 ek1 = *(const float4*)(ekp + 1 * SS);
        float4 ek2 = *(const float4*)(ekp + 2 * SS);
        float4 ek3 = *(const float4*)(ekp + 3 * SS);
        ekp += 4 * SS;
        float4 qa = qpa[kb >> 2];
        float4 qb = qpb[kb >> 2];
        float4 v4 = vap[kb >> 2];
#define GS(Q, E0, E1, E2, E3, ACC) {                                           \
        float y0 = fmaf(Q.x, E0, 1.0f);                                        \
        float y1 = fmaf(Q.y, E1, 1.0f);                                        \
        float y2 = fmaf(Q.z, E2, 1.0f);                                        \
        float y3 = fmaf(Q.w, E3, 1.0f);                                        \
        float d01 = y0 * y1, d23 = y2 * y3;                                    \
        float n01 = fmaf(v4.x, y1, v4.y * y0);                                 \
        float n23 = fmaf(v4.z, y3, v4.w * y2);                                 \
        ACC = fmaf(fmaf(n01, d23, n23 * d01),                                  \
                   __builtin_amdgcn_rcpf(d01 * d23), ACC);                     \
    }
        GS(qa, ek0.x, ek1.x, ek2.x, ek3.x, aA0)
        GS(qa, ek0.y, ek1.y, ek2.y, ek3.y, aA1)
        GS(qa, ek0.z, ek1.z, ek2.z, ek3.z, aA2)
        GS(qa, ek0.w, ek1.w, ek2.w, ek3.w, aA3)
        GS(qb, ek0.x, ek1.x, ek2.x, ek3.x, aB0)
        GS(qb, ek0.y, ek1.y, ek2.y, ek3.y, aB1)
        GS(qb, ek0.z, ek1.z, ek2.z, ek3.z, aB2)
        GS(qb, ek0.w, ek1.w, ek2.w, ek3.w, aB3)
#undef GS
    }

    *(float4*)&wacc[c][2*th + 0][lane * 4] = make_float4(aA0, aA1, aA2, aA3);
    *(float4*)&wacc[c][2*th + 1][lane * 4] = make_float4(aB0, aB1, aB2, aB3);
    __syncthreads();

    // Softmax: wave w -> (t = w&3, sq = w>>2); lane owns s = sq*64+lane
    const int t  = w & 3;
    const int sq = w >> 2;
    const int s  = sq * 64 + lane;
    float wt = 0.f;
    #pragma unroll
    for (int cc = 0; cc < 8; ++cc) wt += wacc[cc][t][s];
    wt *= -2.0f;
    {
        float m = wt;
        #pragma unroll
        for (int off = 32; off > 0; off >>= 1) m = fmaxf(m, __shfl_xor(m, off));
        if (lane == 0) red_m[sq][t] = m;
    }
    __syncthreads();
    const float M = fmaxf(fmaxf(red_m[0][t], red_m[1][t]),
                          fmaxf(red_m[2][t], red_m[3][t]));
    float p = __builtin_amdgcn_exp2f((wt - M) * LOG2E);
    {
        float sm = p;
        #pragma unroll
        for (int off = 32; off > 0; off >>= 1) sm += __shfl_xor(sm, off);
        if (lane == 0) red_s[sq][t] = sm;
    }
    __syncthreads();
    {
        float inv = __builtin_amdgcn_rcpf((red_s[0][t] + red_s[1][t]) +
                                          (red_s[2][t] + red_s[3][t]));
        float sc = p * inv;
        out[(size_t)(b * TT + t0 + t) * SS + s] = sc;
        w_s[t][s] = sc;
    }
    __syncthreads();

    // ctx: v-column = tid&511, t-pair = tid>>9
    const int v   = tid & 511;
    const int th2 = tid >> 9;
    const float* vcol = values + (size_t)b * SS * DD + v;
    const float4* wr0 = (const float4*)&w_s[th2 * 2][0];
    const float4* wr1 = (const float4*)&w_s[th2 * 2 + 1][0];
    float c0 = 0.f, c1 = 0.f;
    #pragma unroll 4
    for (int ss = 0; ss < SS; ss += 4) {
        float4 w0 = wr0[ss >> 2];
        float4 w1 = wr1[ss >> 2];
        float v0 = vcol[(size_t)(ss + 0) * DD];
        float v1 = vcol[(size_t)(ss + 1) * DD];
        float v2 = vcol[(size_t)(ss + 2) * DD];
        float v3 = vcol[(size_t)(ss + 3) * DD];
        c0 = fmaf(w0.x, v0, c0); c1 = fmaf(w1.x, v0, c1);
        c0 = fmaf(w0.y, v1, c0); c1 = fmaf(w1.y, v1, c1);
        c0 = fmaf(w0.z, v2, c0); c1 = fmaf(w1.z, v2, c1);
        c0 = fmaf(w0.w, v3, c0); c1 = fmaf(w1.w, v3, c1);
    }
    float* octx = out + (size_t)BB * TT * SS + (size_t)(b * TT + t0 + th2 * 2) * DD + v;
    octx[0]  = c0;
    octx[DD] = c1;
}

// ---------------------------------------------------------------------------
extern "C" void kernel_launch(void* const* d_in, const int* in_sizes, int n_in,
                              void* d_out, int out_size, void* d_ws, size_t ws_size,
                              hipStream_t stream) {
    const float* query  = (const float*)d_in[0];
    const float* keys   = (const float*)d_in[1];
    const float* values = (const float*)d_in[2];
    const float* Wa     = (const float*)d_in[3];
    const float* va     = (const float*)d_in[4];
    float* out = (float*)d_out;

    float* eq  = (float*)d_ws;                    // 2048 x 512 f32 = 4 MB
    float* ekT = eq + (size_t)BB * TT * DD;       // 8 x 512 x 256 f32 = 4 MB

    gemm_mfma<<<512, 256, 0, stream>>>(query, keys, Wa, eq, ekT);
    attn_fused<<<512, 1024, 0, stream>>>(eq, ekT, va, values, out);
}

// Round 9
// 137.549 us; speedup vs baseline: 1.0206x; 1.0206x over previous
//
#include <hip/hip_runtime.h>
#include <hip/hip_bf16.h>

#define TT   256
#define BB   8
#define SS   256
#define DD   512
#define C2LOG2E 2.8853900817779268f   // 2*log2(e)
#define LOG2E   1.4426950408889634f

typedef __attribute__((ext_vector_type(8))) short bf16x8;
typedef __attribute__((ext_vector_type(4))) float f32x4;

__device__ __forceinline__ unsigned short f2bf(float f) {
    unsigned u = __builtin_bit_cast(unsigned, f);
    u += 0x7FFFu + ((u >> 16) & 1u);
    return (unsigned short)(u >> 16);
}
__device__ __forceinline__ float bf2f(unsigned short h) {
    unsigned u = (unsigned)h << 16;
    return __builtin_bit_cast(float, u);
}

// ---------------------------------------------------------------------------
// MFMA projection GEMMs, split-bf16 (hi/lo). 512 blocks, XCD-pinned.
//   z=0: eq [b*256+t][k] = exp2(c*qp)   row-major
//   z=1: ekT[b][k][s]    = exp2(c*kp)   column-major (transposed via LDS)
// ---------------------------------------------------------------------------
#define LDK 72
__global__ __launch_bounds__(256) void gemm_mfma(const float* __restrict__ query,
                                                 const float* __restrict__ keys,
                                                 const float* __restrict__ Wa,
                                                 float* __restrict__ eq,
                                                 float* __restrict__ ekT) {
    __shared__ __align__(16) unsigned char smem[4 * 64 * LDK * 2];  // 36 KB
    unsigned short* sAh = (unsigned short*)smem;
    unsigned short* sAl = sAh + 64 * LDK;
    unsigned short* sBh = sAl + 64 * LDK;
    unsigned short* sBl = sBh + 64 * LDK;
    float* Cst = (float*)smem;                // reused for z=1 transpose

    const int idx = blockIdx.x;
    const int b   = idx & 7;
    const int r2  = idx >> 3;
    const int q   = r2 & 3;
    const int x   = (r2 >> 2) & 7;
    const int z   = r2 >> 5;
    const bool isQ = (z == 0);

    const float* A  = isQ ? query : keys;
    const int strideR = isQ ? BB * DD : DD;
    const int strideB = isQ ? DD : SS * DD;
    const float* Bsrc = Wa + (isQ ? 0 : DD);

    const int tileN = x * 64;
    const int tid = threadIdx.x;
    const int rb  = tid >> 4;
    const int c4  = tid & 15;

    const float* arow0 = A + (size_t)b * strideB + (size_t)(q * 64) * strideR;
    const float* brow0 = Bsrc + (size_t)tileN * (2 * DD);

    float4 av[4], bv[4];
    #pragma unroll
    for (int i = 0; i < 4; ++i) {
        av[i] = *(const float4*)(arow0 + (size_t)(rb + 16*i) * strideR + c4 * 4);
        bv[i] = *(const float4*)(brow0 + (size_t)(rb + 16*i) * (2*DD) + c4 * 4);
    }

    const int w    = tid >> 6;
    const int lane = tid & 63;
    const int wm   = (w >> 1) * 32;
    const int wn   = (w & 1) * 32;
    const int r16  = lane & 15;
    const int k8   = (lane >> 4) * 8;

    f32x4 acc[2][2] = {};

    for (int kb = 0; kb < DD; kb += 64) {
        __syncthreads();
        #pragma unroll
        for (int i = 0; i < 4; ++i) {
            const int row = rb + 16 * i;
            float4 a = av[i], bq = bv[i];
            ushort4 ah, al, bh, bl;
            ah.x = f2bf(a.x); al.x = f2bf(a.x - bf2f(ah.x));
            ah.y = f2bf(a.y); al.y = f2bf(a.y - bf2f(ah.y));
            ah.z = f2bf(a.z); al.z = f2bf(a.z - bf2f(ah.z));
            ah.w = f2bf(a.w); al.w = f2bf(a.w - bf2f(ah.w));
            bh.x = f2bf(bq.x); bl.x = f2bf(bq.x - bf2f(bh.x));
            bh.y = f2bf(bq.y); bl.y = f2bf(bq.y - bf2f(bh.y));
            bh.z = f2bf(bq.z); bl.z = f2bf(bq.z - bf2f(bh.z));
            bh.w = f2bf(bq.w); bl.w = f2bf(bq.w - bf2f(bh.w));
            *(ushort4*)(sAh + row * LDK + c4 * 4) = ah;
            *(ushort4*)(sAl + row * LDK + c4 * 4) = al;
            *(ushort4*)(sBh + row * LDK + c4 * 4) = bh;
            *(ushort4*)(sBl + row * LDK + c4 * 4) = bl;
        }
        __syncthreads();
        if (kb + 64 < DD) {
            #pragma unroll
            for (int i = 0; i < 4; ++i) {
                av[i] = *(const float4*)(arow0 + (size_t)(rb + 16*i) * strideR + kb + 64 + c4 * 4);
                bv[i] = *(const float4*)(brow0 + (size_t)(rb + 16*i) * (2*DD) + kb + 64 + c4 * 4);
            }
        }
        #pragma unroll
        for (int ks = 0; ks < 2; ++ks) {
            const int ko = ks * 32 + k8;
            bf16x8 a_h[2], a_l[2], b_h[2], b_l[2];
            #pragma unroll
            for (int mt = 0; mt < 2; ++mt) {
                a_h[mt] = *(const bf16x8*)(sAh + (wm + mt*16 + r16) * LDK + ko);
                a_l[mt] = *(const bf16x8*)(sAl + (wm + mt*16 + r16) * LDK + ko);
            }
            #pragma unroll
            for (int nt = 0; nt < 2; ++nt) {
                b_h[nt] = *(const bf16x8*)(sBh + (wn + nt*16 + r16) * LDK + ko);
                b_l[nt] = *(const bf16x8*)(sBl + (wn + nt*16 + r16) * LDK + ko);
            }
            #pragma unroll
            for (int mt = 0; mt < 2; ++mt)
                #pragma unroll
                for (int nt = 0; nt < 2; ++nt) {
                    acc[mt][nt] = __builtin_amdgcn_mfma_f32_16x16x32_bf16(a_h[mt], b_h[nt], acc[mt][nt], 0, 0, 0);
                    acc[mt][nt] = __builtin_amdgcn_mfma_f32_16x16x32_bf16(a_h[mt], b_l[nt], acc[mt][nt], 0, 0, 0);
                    acc[mt][nt] = __builtin_amdgcn_mfma_f32_16x16x32_bf16(a_l[mt], b_h[nt], acc[mt][nt], 0, 0, 0);
                }
        }
    }

    const int crow = (lane >> 4) * 4;
    if (isQ) {
        #pragma unroll
        for (int mt = 0; mt < 2; ++mt)
            #pragma unroll
            for (int nt = 0; nt < 2; ++nt)
                #pragma unroll
                for (int i = 0; i < 4; ++i) {
                    const int m = b * 256 + q * 64 + wm + mt*16 + crow + i;
                    const int n = tileN + wn + nt*16 + r16;
                    eq[(size_t)m * DD + n] = __builtin_amdgcn_exp2f(acc[mt][nt][i] * C2LOG2E);
                }
    } else {
        __syncthreads();
        #pragma unroll
        for (int mt = 0; mt < 2; ++mt)
            #pragma unroll
            for (int nt = 0; nt < 2; ++nt)
                #pragma unroll
                for (int i = 0; i < 4; ++i)
                    Cst[(wm + mt*16 + crow + i) * 69 + wn + nt*16 + r16] =
                        __builtin_amdgcn_exp2f(acc[mt][nt][i] * C2LOG2E);
        __syncthreads();
        const int n  = tid & 63;       // local k
        const int sg = tid >> 6;       // s-quarter of the 64-row tile
        float* dstp = ekT + (size_t)b * DD * SS + (size_t)(tileN + n) * SS + q * 64 + sg * 16;
        #pragma unroll
        for (int j4 = 0; j4 < 4; ++j4) {
            float4 o;
            o.x = Cst[(sg*16 + j4*4 + 0) * 69 + n];
            o.y = Cst[(sg*16 + j4*4 + 1) * 69 + n];
            o.z = Cst[(sg*16 + j4*4 + 2) * 69 + n];
            o.w = Cst[(sg*16 + j4*4 + 3) * 69 + n];
            *(float4*)(dstp + j4 * 4) = o;
        }
    }
}

// ---------------------------------------------------------------------------
// Fused attention. 1024 blocks x 512 threads (8 waves), XCD-pinned.
// Block = (b, 2 t-rows). Wave w owns k-chunk [64w, 64w+64); lane owns
// s = 4*lane..4*lane+3 (coalesced dwordx4 of ekT per k).
// 4-way k-batched rcp (13 VALU + 1 rcp per 4 k); weight = -2*sum (+const
// dropped by softmax). launch_bounds(512,8): VGPR cap 64 (loop needs ~46,
// R7's bigger loop fit exactly 64) -> 4 blocks/CU, 8 waves/SIMD.
// ---------------------------------------------------------------------------
__global__ __launch_bounds__(512, 8) void attn_fused(const float* __restrict__ eq,
                                                     const float* __restrict__ ekT,
                                                     const float* __restrict__ va,
                                                     const float* __restrict__ values,
                                                     float* __restrict__ out) {
    __shared__ __align__(16) float wacc[8][2][256];  // 16 KB [kchunk][t][s]
    __shared__ __align__(16) float w_s[2][256];      // 2 KB
    __shared__ float red_m[4][2];                    // [sq][t]
    __shared__ float red_s[4][2];

    const int tid  = threadIdx.x;
    const int lane = tid & 63;
    const int w    = tid >> 6;          // 0..7 k-chunk
    const int idx  = blockIdx.x;        // 1024 blocks
    const int b    = idx & 7;           // XCD pin
    const int t0   = (idx >> 3) * 2;
    const int k0   = w * 64;

    const float* ekp = ekT + ((size_t)b * DD + k0) * SS + lane * 4;
    const float4* qpa = (const float4*)(eq + (size_t)(b * TT + t0 + 0) * DD + k0);
    const float4* qpb = (const float4*)(eq + (size_t)(b * TT + t0 + 1) * DD + k0);
    const float4* vap = (const float4*)(va + k0);

    float aA0=0,aA1=0,aA2=0,aA3=0, aB0=0,aB1=0,aB2=0,aB3=0;

    #pragma unroll 4
    for (int kb = 0; kb < 64; kb += 4) {
        float4 ek0 = *(const float4*)(ekp + 0 * SS);
        float4 ek1 = *(const float4*)(ekp + 1 * SS);
        float4 ek2 = *(const float4*)(ekp + 2 * SS);
        float4 ek3 = *(const float4*)(ekp + 3 * SS);
        ekp += 4 * SS;
        float4 qa = qpa[kb >> 2];
        float4 qb = qpb[kb >> 2];
        float4 v4 = vap[kb >> 2];
#define GS(Q, E0, E1, E2, E3, ACC) {                                           \
        float y0 = fmaf(Q.x, E0, 1.0f);                                        \
        float y1 = fmaf(Q.y, E1, 1.0f);                                        \
        float y2 = fmaf(Q.z, E2, 1.0f);                                        \
        float y3 = fmaf(Q.w, E3, 1.0f);                                        \
        float d01 = y0 * y1, d23 = y2 * y3;                                    \
        float n01 = fmaf(v4.x, y1, v4.y * y0);                                 \
        float n23 = fmaf(v4.z, y3, v4.w * y2);                                 \
        ACC = fmaf(fmaf(n01, d23, n23 * d01),                                  \
                   __builtin_amdgcn_rcpf(d01 * d23), ACC);                     \
    }
        GS(qa, ek0.x, ek1.x, ek2.x, ek3.x, aA0)
        GS(qa, ek0.y, ek1.y, ek2.y, ek3.y, aA1)
        GS(qa, ek0.z, ek1.z, ek2.z, ek3.z, aA2)
        GS(qa, ek0.w, ek1.w, ek2.w, ek3.w, aA3)
        GS(qb, ek0.x, ek1.x, ek2.x, ek3.x, aB0)
        GS(qb, ek0.y, ek1.y, ek2.y, ek3.y, aB1)
        GS(qb, ek0.z, ek1.z, ek2.z, ek3.z, aB2)
        GS(qb, ek0.w, ek1.w, ek2.w, ek3.w, aB3)
#undef GS
    }

    *(float4*)&wacc[w][0][lane * 4] = make_float4(aA0, aA1, aA2, aA3);
    *(float4*)&wacc[w][1][lane * 4] = make_float4(aB0, aB1, aB2, aB3);
    __syncthreads();

    // Softmax: wave w -> (t = w&1, sq = w>>1); lane owns s = sq*64+lane
    const int t  = w & 1;
    const int sq = w >> 1;
    const int s  = sq * 64 + lane;
    float wt = 0.f;
    #pragma unroll
    for (int cc = 0; cc < 8; ++cc) wt += wacc[cc][t][s];
    wt *= -2.0f;
    {
        float m = wt;
        #pragma unroll
        for (int off = 32; off > 0; off >>= 1) m = fmaxf(m, __shfl_xor(m, off));
        if (lane == 0) red_m[sq][t] = m;
    }
    __syncthreads();
    const float M = fmaxf(fmaxf(red_m[0][t], red_m[1][t]),
                          fmaxf(red_m[2][t], red_m[3][t]));
    float p = __builtin_amdgcn_exp2f((wt - M) * LOG2E);
    {
        float sm = p;
        #pragma unroll
        for (int off = 32; off > 0; off >>= 1) sm += __shfl_xor(sm, off);
        if (lane == 0) red_s[sq][t] = sm;
    }
    __syncthreads();
    {
        float inv = __builtin_amdgcn_rcpf((red_s[0][t] + red_s[1][t]) +
                                          (red_s[2][t] + red_s[3][t]));
        float sc = p * inv;
        out[(size_t)(b * TT + t0 + t) * SS + s] = sc;
        w_s[t][s] = sc;
    }
    __syncthreads();

    // ctx: thread owns column v = tid (512 = DD), both t-rows
    const float* vcol = values + (size_t)b * SS * DD + tid;
    const float4* wr0 = (const float4*)&w_s[0][0];
    const float4* wr1 = (const float4*)&w_s[1][0];
    float c0 = 0.f, c1 = 0.f;
    #pragma unroll 4
    for (int ss = 0; ss < SS; ss += 4) {
        float4 w0 = wr0[ss >> 2];
        float4 w1 = wr1[ss >> 2];
        float v0 = vcol[(size_t)(ss + 0) * DD];
        float v1 = vcol[(size_t)(ss + 1) * DD];
        float v2 = vcol[(size_t)(ss + 2) * DD];
        float v3 = vcol[(size_t)(ss + 3) * DD];
        c0 = fmaf(w0.x, v0, c0); c1 = fmaf(w1.x, v0, c1);
        c0 = fmaf(w0.y, v1, c0); c1 = fmaf(w1.y, v1, c1);
        c0 = fmaf(w0.z, v2, c0); c1 = fmaf(w1.z, v2, c1);
        c0 = fmaf(w0.w, v3, c0); c1 = fmaf(w1.w, v3, c1);
    }
    float* octx = out + (size_t)BB * TT * SS + (size_t)(b * TT + t0) * DD + tid;
    octx[0]  = c0;
    octx[DD] = c1;
}

// ---------------------------------------------------------------------------
extern "C" void kernel_launch(void* const* d_in, const int* in_sizes, int n_in,
                              void* d_out, int out_size, void* d_ws, size_t ws_size,
                              hipStream_t stream) {
    const float* query  = (const float*)d_in[0];
    const float* keys   = (const float*)d_in[1];
    const float* values = (const float*)d_in[2];
    const float* Wa     = (const float*)d_in[3];
    const float* va     = (const float*)d_in[4];
    float* out = (float*)d_out;

    float* eq  = (float*)d_ws;                    // 2048 x 512 f32 = 4 MB
    float* ekT = eq + (size_t)BB * TT * DD;       // 8 x 512 x 256 f32 = 4 MB

    gemm_mfma<<<512, 256, 0, stream>>>(query, keys, Wa, eq, ekT);
    attn_fused<<<1024, 512, 0, stream>>>(eq, ekT, va, values, out);
}

// Round 10
// 72.668 us; speedup vs baseline: 1.9318x; 1.8929x over previous
//
#include <hip/hip_runtime.h>
#include <hip/hip_bf16.h>

#define TT   256
#define BB   8
#define SS   256
#define DD   512
#define C2LOG2E 2.8853900817779268f   // 2*log2(e)
#define LOG2E   1.4426950408889634f

typedef __attribute__((ext_vector_type(8))) short bf16x8;
typedef __attribute__((ext_vector_type(4))) float f32x4;

__device__ __forceinline__ unsigned short f2bf(float f) {
    unsigned u = __builtin_bit_cast(unsigned, f);
    u += 0x7FFFu + ((u >> 16) & 1u);
    return (unsigned short)(u >> 16);
}
__device__ __forceinline__ float bf2f(unsigned short h) {
    unsigned u = (unsigned)h << 16;
    return __builtin_bit_cast(float, u);
}

// ---------------------------------------------------------------------------
// MFMA projection GEMMs, split-bf16 (hi/lo). 512 blocks, XCD-pinned.
//   z=0: eq [b*256+t][k] = exp2(c*qp)   row-major
//   z=1: ekT[b][k][s]    = exp2(c*kp)   column-major (transposed via LDS)
// ---------------------------------------------------------------------------
#define LDK 72
__global__ __launch_bounds__(256) void gemm_mfma(const float* __restrict__ query,
                                                 const float* __restrict__ keys,
                                                 const float* __restrict__ Wa,
                                                 float* __restrict__ eq,
                                                 float* __restrict__ ekT) {
    __shared__ __align__(16) unsigned char smem[4 * 64 * LDK * 2];  // 36 KB
    unsigned short* sAh = (unsigned short*)smem;
    unsigned short* sAl = sAh + 64 * LDK;
    unsigned short* sBh = sAl + 64 * LDK;
    unsigned short* sBl = sBh + 64 * LDK;
    float* Cst = (float*)smem;                // reused for z=1 transpose

    const int idx = blockIdx.x;
    const int b   = idx & 7;
    const int r2  = idx >> 3;
    const int q   = r2 & 3;
    const int x   = (r2 >> 2) & 7;
    const int z   = r2 >> 5;
    const bool isQ = (z == 0);

    const float* A  = isQ ? query : keys;
    const int strideR = isQ ? BB * DD : DD;
    const int strideB = isQ ? DD : SS * DD;
    const float* Bsrc = Wa + (isQ ? 0 : DD);

    const int tileN = x * 64;
    const int tid = threadIdx.x;
    const int rb  = tid >> 4;
    const int c4  = tid & 15;

    const float* arow0 = A + (size_t)b * strideB + (size_t)(q * 64) * strideR;
    const float* brow0 = Bsrc + (size_t)tileN * (2 * DD);

    float4 av[4], bv[4];
    #pragma unroll
    for (int i = 0; i < 4; ++i) {
        av[i] = *(const float4*)(arow0 + (size_t)(rb + 16*i) * strideR + c4 * 4);
        bv[i] = *(const float4*)(brow0 + (size_t)(rb + 16*i) * (2*DD) + c4 * 4);
    }

    const int w    = tid >> 6;
    const int lane = tid & 63;
    const int wm   = (w >> 1) * 32;
    const int wn   = (w & 1) * 32;
    const int r16  = lane & 15;
    const int k8   = (lane >> 4) * 8;

    f32x4 acc[2][2] = {};

    for (int kb = 0; kb < DD; kb += 64) {
        __syncthreads();
        #pragma unroll
        for (int i = 0; i < 4; ++i) {
            const int row = rb + 16 * i;
            float4 a = av[i], bq = bv[i];
            ushort4 ah, al, bh, bl;
            ah.x = f2bf(a.x); al.x = f2bf(a.x - bf2f(ah.x));
            ah.y = f2bf(a.y); al.y = f2bf(a.y - bf2f(ah.y));
            ah.z = f2bf(a.z); al.z = f2bf(a.z - bf2f(ah.z));
            ah.w = f2bf(a.w); al.w = f2bf(a.w - bf2f(ah.w));
            bh.x = f2bf(bq.x); bl.x = f2bf(bq.x - bf2f(bh.x));
            bh.y = f2bf(bq.y); bl.y = f2bf(bq.y - bf2f(bh.y));
            bh.z = f2bf(bq.z); bl.z = f2bf(bq.z - bf2f(bh.z));
            bh.w = f2bf(bq.w); bl.w = f2bf(bq.w - bf2f(bh.w));
            *(ushort4*)(sAh + row * LDK + c4 * 4) = ah;
            *(ushort4*)(sAl + row * LDK + c4 * 4) = al;
            *(ushort4*)(sBh + row * LDK + c4 * 4) = bh;
            *(ushort4*)(sBl + row * LDK + c4 * 4) = bl;
        }
        __syncthreads();
        if (kb + 64 < DD) {
            #pragma unroll
            for (int i = 0; i < 4; ++i) {
                av[i] = *(const float4*)(arow0 + (size_t)(rb + 16*i) * strideR + kb + 64 + c4 * 4);
                bv[i] = *(const float4*)(brow0 + (size_t)(rb + 16*i) * (2*DD) + kb + 64 + c4 * 4);
            }
        }
        #pragma unroll
        for (int ks = 0; ks < 2; ++ks) {
            const int ko = ks * 32 + k8;
            bf16x8 a_h[2], a_l[2], b_h[2], b_l[2];
            #pragma unroll
            for (int mt = 0; mt < 2; ++mt) {
                a_h[mt] = *(const bf16x8*)(sAh + (wm + mt*16 + r16) * LDK + ko);
                a_l[mt] = *(const bf16x8*)(sAl + (wm + mt*16 + r16) * LDK + ko);
            }
            #pragma unroll
            for (int nt = 0; nt < 2; ++nt) {
                b_h[nt] = *(const bf16x8*)(sBh + (wn + nt*16 + r16) * LDK + ko);
                b_l[nt] = *(const bf16x8*)(sBl + (wn + nt*16 + r16) * LDK + ko);
            }
            #pragma unroll
            for (int mt = 0; mt < 2; ++mt)
                #pragma unroll
                for (int nt = 0; nt < 2; ++nt) {
                    acc[mt][nt] = __builtin_amdgcn_mfma_f32_16x16x32_bf16(a_h[mt], b_h[nt], acc[mt][nt], 0, 0, 0);
                    acc[mt][nt] = __builtin_amdgcn_mfma_f32_16x16x32_bf16(a_h[mt], b_l[nt], acc[mt][nt], 0, 0, 0);
                    acc[mt][nt] = __builtin_amdgcn_mfma_f32_16x16x32_bf16(a_l[mt], b_h[nt], acc[mt][nt], 0, 0, 0);
                }
        }
    }

    const int crow = (lane >> 4) * 4;
    if (isQ) {
        #pragma unroll
        for (int mt = 0; mt < 2; ++mt)
            #pragma unroll
            for (int nt = 0; nt < 2; ++nt)
                #pragma unroll
                for (int i = 0; i < 4; ++i) {
                    const int m = b * 256 + q * 64 + wm + mt*16 + crow + i;
                    const int n = tileN + wn + nt*16 + r16;
                    eq[(size_t)m * DD + n] = __builtin_amdgcn_exp2f(acc[mt][nt][i] * C2LOG2E);
                }
    } else {
        __syncthreads();
        #pragma unroll
        for (int mt = 0; mt < 2; ++mt)
            #pragma unroll
            for (int nt = 0; nt < 2; ++nt)
                #pragma unroll
                for (int i = 0; i < 4; ++i)
                    Cst[(wm + mt*16 + crow + i) * 69 + wn + nt*16 + r16] =
                        __builtin_amdgcn_exp2f(acc[mt][nt][i] * C2LOG2E);
        __syncthreads();
        const int n  = tid & 63;       // local k
        const int sg = tid >> 6;       // s-quarter of the 64-row tile
        float* dstp = ekT + (size_t)b * DD * SS + (size_t)(tileN + n) * SS + q * 64 + sg * 16;
        #pragma unroll
        for (int j4 = 0; j4 < 4; ++j4) {
            float4 o;
            o.x = Cst[(sg*16 + j4*4 + 0) * 69 + n];
            o.y = Cst[(sg*16 + j4*4 + 1) * 69 + n];
            o.z = Cst[(sg*16 + j4*4 + 2) * 69 + n];
            o.w = Cst[(sg*16 + j4*4 + 3) * 69 + n];
            *(float4*)(dstp + j4 * 4) = o;
        }
    }
}

// ---------------------------------------------------------------------------
// Fused attention. 512 blocks x 1024 threads (16 waves), XCD-pinned.
// Wave w = (th = w>>3, c = w&7): computes t-rows {t0+2th, t0+2th+1} over
// k-chunk [64c, 64c+64), lane owns s = 4*lane..4*lane+3 (coalesced dwordx4).
// 4-way k-batched rcp (13 VALU + 1 rcp per 4 k); weight = -2*sum (+const
// dropped by softmax). launch_bounds(1024,2): VGPR cap 128, natural ~50-64
// (arg2=8 empirically caps at 32 -> catastrophic spill, R8/R9 lesson).
// ---------------------------------------------------------------------------
__global__ __launch_bounds__(1024, 2) void attn_fused(const float* __restrict__ eq,
                                                      const float* __restrict__ ekT,
                                                      const float* __restrict__ va,
                                                      const float* __restrict__ values,
                                                      float* __restrict__ out) {
    __shared__ __align__(16) float wacc[8][4][256];  // 32 KB [kchunk][t][s]
    __shared__ __align__(16) float w_s[4][256];      // 4 KB
    __shared__ float red_m[4][4];                    // [sq][t]
    __shared__ float red_s[4][4];

    const int tid  = threadIdx.x;
    const int lane = tid & 63;
    const int w    = tid >> 6;          // 0..15
    const int c    = w & 7;             // k-chunk
    const int th   = w >> 3;            // t-half
    const int idx  = blockIdx.x;
    const int b    = idx & 7;           // XCD pin
    const int t0   = (idx >> 3) * 4;
    const int k0   = c * 64;

    const float* ekp = ekT + ((size_t)b * DD + k0) * SS + lane * 4;
    const float4* qpa = (const float4*)(eq + (size_t)(b * TT + t0 + 2*th + 0) * DD + k0);
    const float4* qpb = (const float4*)(eq + (size_t)(b * TT + t0 + 2*th + 1) * DD + k0);
    const float4* vap = (const float4*)(va + k0);

    float aA0=0,aA1=0,aA2=0,aA3=0, aB0=0,aB1=0,aB2=0,aB3=0;

    #pragma unroll 4
    for (int kb = 0; kb < 64; kb += 4) {
        float4 ek0 = *(const float4*)(ekp + 0 * SS);
        float4 ek1 = *(const float4*)(ekp + 1 * SS);
        float4 ek2 = *(const float4*)(ekp + 2 * SS);
        float4 ek3 = *(const float4*)(ekp + 3 * SS);
        ekp += 4 * SS;
        float4 qa = qpa[kb >> 2];
        float4 qb = qpb[kb >> 2];
        float4 v4 = vap[kb >> 2];
#define GS(Q, E0, E1, E2, E3, ACC) {                                           \
        float y0 = fmaf(Q.x, E0, 1.0f);                                        \
        float y1 = fmaf(Q.y, E1, 1.0f);                                        \
        float y2 = fmaf(Q.z, E2, 1.0f);                                        \
        float y3 = fmaf(Q.w, E3, 1.0f);                                        \
        float d01 = y0 * y1, d23 = y2 * y3;                                    \
        float n01 = fmaf(v4.x, y1, v4.y * y0);                                 \
        float n23 = fmaf(v4.z, y3, v4.w * y2);                                 \
        ACC = fmaf(fmaf(n01, d23, n23 * d01),                                  \
                   __builtin_amdgcn_rcpf(d01 * d23), ACC);                     \
    }
        GS(qa, ek0.x, ek1.x, ek2.x, ek3.x, aA0)
        GS(qa, ek0.y, ek1.y, ek2.y, ek3.y, aA1)
        GS(qa, ek0.z, ek1.z, ek2.z, ek3.z, aA2)
        GS(qa, ek0.w, ek1.w, ek2.w, ek3.w, aA3)
        GS(qb, ek0.x, ek1.x, ek2.x, ek3.x, aB0)
        GS(qb, ek0.y, ek1.y, ek2.y, ek3.y, aB1)
        GS(qb, ek0.z, ek1.z, ek2.z, ek3.z, aB2)
        GS(qb, ek0.w, ek1.w, ek2.w, ek3.w, aB3)
#undef GS
    }

    *(float4*)&wacc[c][2*th + 0][lane * 4] = make_float4(aA0, aA1, aA2, aA3);
    *(float4*)&wacc[c][2*th + 1][lane * 4] = make_float4(aB0, aB1, aB2, aB3);
    __syncthreads();

    // Softmax: wave w -> (t = w&3, sq = w>>2); lane owns s = sq*64+lane
    const int t  = w & 3;
    const int sq = w >> 2;
    const int s  = sq * 64 + lane;
    float wt = 0.f;
    #pragma unroll
    for (int cc = 0; cc < 8; ++cc) wt += wacc[cc][t][s];
    wt *= -2.0f;
    {
        float m = wt;
        #pragma unroll
        for (int off = 32; off > 0; off >>= 1) m = fmaxf(m, __shfl_xor(m, off));
        if (lane == 0) red_m[sq][t] = m;
    }
    __syncthreads();
    const float M = fmaxf(fmaxf(red_m[0][t], red_m[1][t]),
                          fmaxf(red_m[2][t], red_m[3][t]));
    float p = __builtin_amdgcn_exp2f((wt - M) * LOG2E);
    {
        float sm = p;
        #pragma unroll
        for (int off = 32; off > 0; off >>= 1) sm += __shfl_xor(sm, off);
        if (lane == 0) red_s[sq][t] = sm;
    }
    __syncthreads();
    {
        float inv = __builtin_amdgcn_rcpf((red_s[0][t] + red_s[1][t]) +
                                          (red_s[2][t] + red_s[3][t]));
        float sc = p * inv;
        out[(size_t)(b * TT + t0 + t) * SS + s] = sc;
        w_s[t][s] = sc;
    }
    __syncthreads();

    // ctx: v-column = tid&511, t-pair = tid>>9
    const int v   = tid & 511;
    const int th2 = tid >> 9;
    const float* vcol = values + (size_t)b * SS * DD + v;
    const float4* wr0 = (const float4*)&w_s[th2 * 2][0];
    const float4* wr1 = (const float4*)&w_s[th2 * 2 + 1][0];
    float c0 = 0.f, c1 = 0.f;
    #pragma unroll 4
    for (int ss = 0; ss < SS; ss += 4) {
        float4 w0 = wr0[ss >> 2];
        float4 w1 = wr1[ss >> 2];
        float v0 = vcol[(size_t)(ss + 0) * DD];
        float v1 = vcol[(size_t)(ss + 1) * DD];
        float v2 = vcol[(size_t)(ss + 2) * DD];
        float v3 = vcol[(size_t)(ss + 3) * DD];
        c0 = fmaf(w0.x, v0, c0); c1 = fmaf(w1.x, v0, c1);
        c0 = fmaf(w0.y, v1, c0); c1 = fmaf(w1.y, v1, c1);
        c0 = fmaf(w0.z, v2, c0); c1 = fmaf(w1.z, v2, c1);
        c0 = fmaf(w0.w, v3, c0); c1 = fmaf(w1.w, v3, c1);
    }
    float* octx = out + (size_t)BB * TT * SS + (size_t)(b * TT + t0 + th2 * 2) * DD + v;
    octx[0]  = c0;
    octx[DD] = c1;
}

// ---------------------------------------------------------------------------
extern "C" void kernel_launch(void* const* d_in, const int* in_sizes, int n_in,
                              void* d_out, int out_size, void* d_ws, size_t ws_size,
                              hipStream_t stream) {
    const float* query  = (const float*)d_in[0];
    const float* keys   = (const float*)d_in[1];
    const float* values = (const float*)d_in[2];
    const float* Wa     = (const float*)d_in[3];
    const float* va     = (const float*)d_in[4];
    float* out = (float*)d_out;

    float* eq  = (float*)d_ws;                    // 2048 x 512 f32 = 4 MB
    float* ekT = eq + (size_t)BB * TT * DD;       // 8 x 512 x 256 f32 = 4 MB

    gemm_mfma<<<512, 256, 0, stream>>>(query, keys, Wa, eq, ekT);
    attn_fused<<<512, 1024, 0, stream>>>(eq, ekT, va, values, out);
}

// Round 11
// 69.237 us; speedup vs baseline: 2.0275x; 1.0495x over previous
//
#include <hip/hip_runtime.h>
#include <hip/hip_bf16.h>

#define TT   256
#define BB   8
#define SS   256
#define DD   512
#define C2LOG2E 2.8853900817779268f   // 2*log2(e)
#define LOG2E   1.4426950408889634f

typedef __attribute__((ext_vector_type(8))) short bf16x8;
typedef __attribute__((ext_vector_type(4))) float f32x4;

__device__ __forceinline__ unsigned short f2bf(float f) {
    unsigned u = __builtin_bit_cast(unsigned, f);
    u += 0x7FFFu + ((u >> 16) & 1u);
    return (unsigned short)(u >> 16);
}
__device__ __forceinline__ float bf2f(unsigned short h) {
    unsigned u = (unsigned)h << 16;
    return __builtin_bit_cast(float, u);
}

// ---------------------------------------------------------------------------
// MFMA projection GEMMs, split-bf16 (hi/lo). 512 blocks, XCD-pinned.
//   z=0: eq [b*256+t][k] = exp2(c*qp)   row-major
//   z=1: ekT[b][k][s]    = exp2(c*kp)   column-major (transposed via LDS)
// ---------------------------------------------------------------------------
#define LDK 72
__global__ __launch_bounds__(256) void gemm_mfma(const float* __restrict__ query,
                                                 const float* __restrict__ keys,
                                                 const float* __restrict__ Wa,
                                                 float* __restrict__ eq,
                                                 float* __restrict__ ekT) {
    __shared__ __align__(16) unsigned char smem[4 * 64 * LDK * 2];  // 36 KB
    unsigned short* sAh = (unsigned short*)smem;
    unsigned short* sAl = sAh + 64 * LDK;
    unsigned short* sBh = sAl + 64 * LDK;
    unsigned short* sBl = sBh + 64 * LDK;
    float* Cst = (float*)smem;                // reused for z=1 transpose

    const int idx = blockIdx.x;
    const int b   = idx & 7;
    const int r2  = idx >> 3;
    const int q   = r2 & 3;
    const int x   = (r2 >> 2) & 7;
    const int z   = r2 >> 5;
    const bool isQ = (z == 0);

    const float* A  = isQ ? query : keys;
    const int strideR = isQ ? BB * DD : DD;
    const int strideB = isQ ? DD : SS * DD;
    const float* Bsrc = Wa + (isQ ? 0 : DD);

    const int tileN = x * 64;
    const int tid = threadIdx.x;
    const int rb  = tid >> 4;
    const int c4  = tid & 15;

    const float* arow0 = A + (size_t)b * strideB + (size_t)(q * 64) * strideR;
    const float* brow0 = Bsrc + (size_t)tileN * (2 * DD);

    float4 av[4], bv[4];
    #pragma unroll
    for (int i = 0; i < 4; ++i) {
        av[i] = *(const float4*)(arow0 + (size_t)(rb + 16*i) * strideR + c4 * 4);
        bv[i] = *(const float4*)(brow0 + (size_t)(rb + 16*i) * (2*DD) + c4 * 4);
    }

    const int w    = tid >> 6;
    const int lane = tid & 63;
    const int wm   = (w >> 1) * 32;
    const int wn   = (w & 1) * 32;
    const int r16  = lane & 15;
    const int k8   = (lane >> 4) * 8;

    f32x4 acc[2][2] = {};

    for (int kb = 0; kb < DD; kb += 64) {
        __syncthreads();
        #pragma unroll
        for (int i = 0; i < 4; ++i) {
            const int row = rb + 16 * i;
            float4 a = av[i], bq = bv[i];
            ushort4 ah, al, bh, bl;
            ah.x = f2bf(a.x); al.x = f2bf(a.x - bf2f(ah.x));
            ah.y = f2bf(a.y); al.y = f2bf(a.y - bf2f(ah.y));
            ah.z = f2bf(a.z); al.z = f2bf(a.z - bf2f(ah.z));
            ah.w = f2bf(a.w); al.w = f2bf(a.w - bf2f(ah.w));
            bh.x = f2bf(bq.x); bl.x = f2bf(bq.x - bf2f(bh.x));
            bh.y = f2bf(bq.y); bl.y = f2bf(bq.y - bf2f(bh.y));
            bh.z = f2bf(bq.z); bl.z = f2bf(bq.z - bf2f(bh.z));
            bh.w = f2bf(bq.w); bl.w = f2bf(bq.w - bf2f(bh.w));
            *(ushort4*)(sAh + row * LDK + c4 * 4) = ah;
            *(ushort4*)(sAl + row * LDK + c4 * 4) = al;
            *(ushort4*)(sBh + row * LDK + c4 * 4) = bh;
            *(ushort4*)(sBl + row * LDK + c4 * 4) = bl;
        }
        __syncthreads();
        if (kb + 64 < DD) {
            #pragma unroll
            for (int i = 0; i < 4; ++i) {
                av[i] = *(const float4*)(arow0 + (size_t)(rb + 16*i) * strideR + kb + 64 + c4 * 4);
                bv[i] = *(const float4*)(brow0 + (size_t)(rb + 16*i) * (2*DD) + kb + 64 + c4 * 4);
            }
        }
        #pragma unroll
        for (int ks = 0; ks < 2; ++ks) {
            const int ko = ks * 32 + k8;
            bf16x8 a_h[2], a_l[2], b_h[2], b_l[2];
            #pragma unroll
            for (int mt = 0; mt < 2; ++mt) {
                a_h[mt] = *(const bf16x8*)(sAh + (wm + mt*16 + r16) * LDK + ko);
                a_l[mt] = *(const bf16x8*)(sAl + (wm + mt*16 + r16) * LDK + ko);
            }
            #pragma unroll
            for (int nt = 0; nt < 2; ++nt) {
                b_h[nt] = *(const bf16x8*)(sBh + (wn + nt*16 + r16) * LDK + ko);
                b_l[nt] = *(const bf16x8*)(sBl + (wn + nt*16 + r16) * LDK + ko);
            }
            #pragma unroll
            for (int mt = 0; mt < 2; ++mt)
                #pragma unroll
                for (int nt = 0; nt < 2; ++nt) {
                    acc[mt][nt] = __builtin_amdgcn_mfma_f32_16x16x32_bf16(a_h[mt], b_h[nt], acc[mt][nt], 0, 0, 0);
                    acc[mt][nt] = __builtin_amdgcn_mfma_f32_16x16x32_bf16(a_h[mt], b_l[nt], acc[mt][nt], 0, 0, 0);
                    acc[mt][nt] = __builtin_amdgcn_mfma_f32_16x16x32_bf16(a_l[mt], b_h[nt], acc[mt][nt], 0, 0, 0);
                }
        }
    }

    const int crow = (lane >> 4) * 4;
    if (isQ) {
        #pragma unroll
        for (int mt = 0; mt < 2; ++mt)
            #pragma unroll
            for (int nt = 0; nt < 2; ++nt)
                #pragma unroll
                for (int i = 0; i < 4; ++i) {
                    const int m = b * 256 + q * 64 + wm + mt*16 + crow + i;
                    const int n = tileN + wn + nt*16 + r16;
                    eq[(size_t)m * DD + n] = __builtin_amdgcn_exp2f(acc[mt][nt][i] * C2LOG2E);
                }
    } else {
        __syncthreads();
        #pragma unroll
        for (int mt = 0; mt < 2; ++mt)
            #pragma unroll
            for (int nt = 0; nt < 2; ++nt)
                #pragma unroll
                for (int i = 0; i < 4; ++i)
                    Cst[(wm + mt*16 + crow + i) * 69 + wn + nt*16 + r16] =
                        __builtin_amdgcn_exp2f(acc[mt][nt][i] * C2LOG2E);
        __syncthreads();
        const int n  = tid & 63;       // local k
        const int sg = tid >> 6;       // s-quarter of the 64-row tile
        float* dstp = ekT + (size_t)b * DD * SS + (size_t)(tileN + n) * SS + q * 64 + sg * 16;
        #pragma unroll
        for (int j4 = 0; j4 < 4; ++j4) {
            float4 o;
            o.x = Cst[(sg*16 + j4*4 + 0) * 69 + n];
            o.y = Cst[(sg*16 + j4*4 + 1) * 69 + n];
            o.z = Cst[(sg*16 + j4*4 + 2) * 69 + n];
            o.w = Cst[(sg*16 + j4*4 + 3) * 69 + n];
            *(float4*)(dstp + j4 * 4) = o;
        }
    }
}

// ---------------------------------------------------------------------------
// Fused attention. 512 blocks x 1024 threads (16 waves), XCD-pinned.
// Wave w = (th = w>>3, kq = w&7): t-rows {t0+2th, t0+2th+1}, k-chunk
// [64kq, 64kq+64). Lane owns s = 4*lane..+3 (coalesced ekT dwordx4).
// q/va come from LDS as wave-uniform broadcasts (eq staged TRANSPOSED
// [k][t] so a ds_read_b64 yields both t's of the pair). 2-way rcp batch:
// va0/y0 + va1/y1 = n * rcp(y0*y1), y = 1 + eq*ek  (5 VALU + 1 rcp / 2 el).
// Lean register design (~34 live); launch_bounds(1024,6) caps VGPR at 42
// (cap>need+8, R8 lesson) -> target 4-5 waves/SIMD vs R7's 3.
// ---------------------------------------------------------------------------
__global__ __launch_bounds__(1024, 6) void attn_fused(const float* __restrict__ eq,
                                                      const float* __restrict__ ekT,
                                                      const float* __restrict__ va,
                                                      const float* __restrict__ values,
                                                      float* __restrict__ out) {
    __shared__ __align__(16) float eq_sT[512][4];    // [k][t] 8 KB
    __shared__ __align__(16) float va_s[512];        // 2 KB
    __shared__ __align__(16) float wacc[8][4][256];  // 32 KB [kchunk][t][s]
    __shared__ __align__(16) float w_s[4][256];      // 4 KB
    __shared__ float red_m[4][4];                    // [sq][t]
    __shared__ float red_s[4][4];

    const int tid  = threadIdx.x;
    const int lane = tid & 63;
    const int w    = tid >> 6;          // 0..15
    const int kq   = w & 7;             // k-chunk
    const int th   = w >> 3;            // t-half
    const int idx  = blockIdx.x;
    const int b    = idx & 7;           // XCD pin
    const int t0   = (idx >> 3) * 4;
    const int k0   = kq * 64;

    // Stage eq transposed ([k][t], coalesced per t-row) + raw va
    if (tid < 512) {
        const int kk = tid;
        #pragma unroll
        for (int t = 0; t < 4; ++t)
            eq_sT[kk][t] = eq[(size_t)(b * TT + t0 + t) * DD + kk];
    } else {
        const int kk = tid - 512;
        va_s[kk] = va[kk];
    }
    __syncthreads();

    const float* ekp = ekT + ((size_t)b * DD + k0) * SS + lane * 4;

    float aA0=0,aA1=0,aA2=0,aA3=0, aB0=0,aB1=0,aB2=0,aB3=0;

    for (int kk = 0; kk < 64; kk += 2) {
        float4 ek0 = *(const float4*)(ekp);
        float4 ek1 = *(const float4*)(ekp + SS);
        ekp += 2 * SS;
        // wave-uniform LDS broadcasts
        float2 qA = *(const float2*)&eq_sT[k0 + kk][2 * th];      // t-pair @ k
        float2 qB = *(const float2*)&eq_sT[k0 + kk + 1][2 * th];  // t-pair @ k+1
        float2 vv = *(const float2*)&va_s[k0 + kk];
#define GS2(QK0, QK1, E0, E1, ACC) {                                           \
        float y0 = fmaf(QK0, E0, 1.0f);                                        \
        float y1 = fmaf(QK1, E1, 1.0f);                                        \
        float n  = fmaf(vv.x, y1, vv.y * y0);                                  \
        ACC = fmaf(n, __builtin_amdgcn_rcpf(y0 * y1), ACC);                    \
    }
        GS2(qA.x, qB.x, ek0.x, ek1.x, aA0)
        GS2(qA.x, qB.x, ek0.y, ek1.y, aA1)
        GS2(qA.x, qB.x, ek0.z, ek1.z, aA2)
        GS2(qA.x, qB.x, ek0.w, ek1.w, aA3)
        GS2(qA.y, qB.y, ek0.x, ek1.x, aB0)
        GS2(qA.y, qB.y, ek0.y, ek1.y, aB1)
        GS2(qA.y, qB.y, ek0.z, ek1.z, aB2)
        GS2(qA.y, qB.y, ek0.w, ek1.w, aB3)
#undef GS2
    }

    *(float4*)&wacc[kq][2*th + 0][lane * 4] = make_float4(aA0, aA1, aA2, aA3);
    *(float4*)&wacc[kq][2*th + 1][lane * 4] = make_float4(aB0, aB1, aB2, aB3);
    __syncthreads();

    // Softmax: wave w -> (t = w&3, sq = w>>2); lane owns s = sq*64+lane
    const int t  = w & 3;
    const int sq = w >> 2;
    const int s  = sq * 64 + lane;
    float wt = 0.f;
    #pragma unroll
    for (int cc = 0; cc < 8; ++cc) wt += wacc[cc][t][s];
    wt *= -2.0f;
    {
        float m = wt;
        #pragma unroll
        for (int off = 32; off > 0; off >>= 1) m = fmaxf(m, __shfl_xor(m, off));
        if (lane == 0) red_m[sq][t] = m;
    }
    __syncthreads();
    const float M = fmaxf(fmaxf(red_m[0][t], red_m[1][t]),
                          fmaxf(red_m[2][t], red_m[3][t]));
    float p = __builtin_amdgcn_exp2f((wt - M) * LOG2E);
    {
        float sm = p;
        #pragma unroll
        for (int off = 32; off > 0; off >>= 1) sm += __shfl_xor(sm, off);
        if (lane == 0) red_s[sq][t] = sm;
    }
    __syncthreads();
    {
        float inv = __builtin_amdgcn_rcpf((red_s[0][t] + red_s[1][t]) +
                                          (red_s[2][t] + red_s[3][t]));
        float sc = p * inv;
        out[(size_t)(b * TT + t0 + t) * SS + s] = sc;
        w_s[t][s] = sc;
    }
    __syncthreads();

    // ctx: v-column = tid&511, t-pair = tid>>9
    const int v   = tid & 511;
    const int th2 = tid >> 9;
    const float* vcol = values + (size_t)b * SS * DD + v;
    const float4* wr0 = (const float4*)&w_s[th2 * 2][0];
    const float4* wr1 = (const float4*)&w_s[th2 * 2 + 1][0];
    float c0 = 0.f, c1 = 0.f;
    #pragma unroll 4
    for (int ss = 0; ss < SS; ss += 4) {
        float4 w0 = wr0[ss >> 2];
        float4 w1 = wr1[ss >> 2];
        float v0 = vcol[(size_t)(ss + 0) * DD];
        float v1 = vcol[(size_t)(ss + 1) * DD];
        float v2 = vcol[(size_t)(ss + 2) * DD];
        float v3 = vcol[(size_t)(ss + 3) * DD];
        c0 = fmaf(w0.x, v0, c0); c1 = fmaf(w1.x, v0, c1);
        c0 = fmaf(w0.y, v1, c0); c1 = fmaf(w1.y, v1, c1);
        c0 = fmaf(w0.z, v2, c0); c1 = fmaf(w1.z, v2, c1);
        c0 = fmaf(w0.w, v3, c0); c1 = fmaf(w1.w, v3, c1);
    }
    float* octx = out + (size_t)BB * TT * SS + (size_t)(b * TT + t0 + th2 * 2) * DD + v;
    octx[0]  = c0;
    octx[DD] = c1;
}

// ---------------------------------------------------------------------------
extern "C" void kernel_launch(void* const* d_in, const int* in_sizes, int n_in,
                              void* d_out, int out_size, void* d_ws, size_t ws_size,
                              hipStream_t stream) {
    const float* query  = (const float*)d_in[0];
    const float* keys   = (const float*)d_in[1];
    const float* values = (const float*)d_in[2];
    const float* Wa     = (const float*)d_in[3];
    const float* va     = (const float*)d_in[4];
    float* out = (float*)d_out;

    float* eq  = (float*)d_ws;                    // 2048 x 512 f32 = 4 MB
    float* ekT = eq + (size_t)BB * TT * DD;       // 8 x 512 x 256 f32 = 4 MB

    gemm_mfma<<<512, 256, 0, stream>>>(query, keys, Wa, eq, ekT);
    attn_fused<<<512, 1024, 0, stream>>>(eq, ekT, va, values, out);
}

// Round 12
// 64.154 us; speedup vs baseline: 2.1881x; 1.0792x over previous
//
#include <hip/hip_runtime.h>
#include <hip/hip_bf16.h>

#define TT   256
#define BB   8
#define SS   256
#define DD   512
#define C2LOG2E 2.8853900817779268f   // 2*log2(e)
#define LOG2E   1.4426950408889634f

typedef __attribute__((ext_vector_type(8))) short bf16x8;
typedef __attribute__((ext_vector_type(4))) float f32x4;

__device__ __forceinline__ unsigned short f2bf(float f) {
    unsigned u = __builtin_bit_cast(unsigned, f);
    u += 0x7FFFu + ((u >> 16) & 1u);
    return (unsigned short)(u >> 16);
}
__device__ __forceinline__ float bf2f(unsigned short h) {
    unsigned u = (unsigned)h << 16;
    return __builtin_bit_cast(float, u);
}

// ---------------------------------------------------------------------------
// MFMA projection GEMMs, split-bf16 (hi/lo). 512 blocks, XCD-pinned.
//   z=0: eq [b*256+t][k] = exp2(c*qp)   row-major
//   z=1: ekT[b][k][s]    = exp2(c*kp)   column-major (transposed via LDS)
// ---------------------------------------------------------------------------
#define LDK 72
__global__ __launch_bounds__(256) void gemm_mfma(const float* __restrict__ query,
                                                 const float* __restrict__ keys,
                                                 const float* __restrict__ Wa,
                                                 float* __restrict__ eq,
                                                 float* __restrict__ ekT) {
    __shared__ __align__(16) unsigned char smem[4 * 64 * LDK * 2];  // 36 KB
    unsigned short* sAh = (unsigned short*)smem;
    unsigned short* sAl = sAh + 64 * LDK;
    unsigned short* sBh = sAl + 64 * LDK;
    unsigned short* sBl = sBh + 64 * LDK;
    float* Cst = (float*)smem;                // reused for z=1 transpose

    const int idx = blockIdx.x;
    const int b   = idx & 7;
    const int r2  = idx >> 3;
    const int q   = r2 & 3;
    const int x   = (r2 >> 2) & 7;
    const int z   = r2 >> 5;
    const bool isQ = (z == 0);

    const float* A  = isQ ? query : keys;
    const int strideR = isQ ? BB * DD : DD;
    const int strideB = isQ ? DD : SS * DD;
    const float* Bsrc = Wa + (isQ ? 0 : DD);

    const int tileN = x * 64;
    const int tid = threadIdx.x;
    const int rb  = tid >> 4;
    const int c4  = tid & 15;

    const float* arow0 = A + (size_t)b * strideB + (size_t)(q * 64) * strideR;
    const float* brow0 = Bsrc + (size_t)tileN * (2 * DD);

    float4 av[4], bv[4];
    #pragma unroll
    for (int i = 0; i < 4; ++i) {
        av[i] = *(const float4*)(arow0 + (size_t)(rb + 16*i) * strideR + c4 * 4);
        bv[i] = *(const float4*)(brow0 + (size_t)(rb + 16*i) * (2*DD) + c4 * 4);
    }

    const int w    = tid >> 6;
    const int lane = tid & 63;
    const int wm   = (w >> 1) * 32;
    const int wn   = (w & 1) * 32;
    const int r16  = lane & 15;
    const int k8   = (lane >> 4) * 8;

    f32x4 acc[2][2] = {};

    for (int kb = 0; kb < DD; kb += 64) {
        __syncthreads();
        #pragma unroll
        for (int i = 0; i < 4; ++i) {
            const int row = rb + 16 * i;
            float4 a = av[i], bq = bv[i];
            ushort4 ah, al, bh, bl;
            ah.x = f2bf(a.x); al.x = f2bf(a.x - bf2f(ah.x));
            ah.y = f2bf(a.y); al.y = f2bf(a.y - bf2f(ah.y));
            ah.z = f2bf(a.z); al.z = f2bf(a.z - bf2f(ah.z));
            ah.w = f2bf(a.w); al.w = f2bf(a.w - bf2f(ah.w));
            bh.x = f2bf(bq.x); bl.x = f2bf(bq.x - bf2f(bh.x));
            bh.y = f2bf(bq.y); bl.y = f2bf(bq.y - bf2f(bh.y));
            bh.z = f2bf(bq.z); bl.z = f2bf(bq.z - bf2f(bh.z));
            bh.w = f2bf(bq.w); bl.w = f2bf(bq.w - bf2f(bh.w));
            *(ushort4*)(sAh + row * LDK + c4 * 4) = ah;
            *(ushort4*)(sAl + row * LDK + c4 * 4) = al;
            *(ushort4*)(sBh + row * LDK + c4 * 4) = bh;
            *(ushort4*)(sBl + row * LDK + c4 * 4) = bl;
        }
        __syncthreads();
        if (kb + 64 < DD) {
            #pragma unroll
            for (int i = 0; i < 4; ++i) {
                av[i] = *(const float4*)(arow0 + (size_t)(rb + 16*i) * strideR + kb + 64 + c4 * 4);
                bv[i] = *(const float4*)(brow0 + (size_t)(rb + 16*i) * (2*DD) + kb + 64 + c4 * 4);
            }
        }
        #pragma unroll
        for (int ks = 0; ks < 2; ++ks) {
            const int ko = ks * 32 + k8;
            bf16x8 a_h[2], a_l[2], b_h[2], b_l[2];
            #pragma unroll
            for (int mt = 0; mt < 2; ++mt) {
                a_h[mt] = *(const bf16x8*)(sAh + (wm + mt*16 + r16) * LDK + ko);
                a_l[mt] = *(const bf16x8*)(sAl + (wm + mt*16 + r16) * LDK + ko);
            }
            #pragma unroll
            for (int nt = 0; nt < 2; ++nt) {
                b_h[nt] = *(const bf16x8*)(sBh + (wn + nt*16 + r16) * LDK + ko);
                b_l[nt] = *(const bf16x8*)(sBl + (wn + nt*16 + r16) * LDK + ko);
            }
            #pragma unroll
            for (int mt = 0; mt < 2; ++mt)
                #pragma unroll
                for (int nt = 0; nt < 2; ++nt) {
                    acc[mt][nt] = __builtin_amdgcn_mfma_f32_16x16x32_bf16(a_h[mt], b_h[nt], acc[mt][nt], 0, 0, 0);
                    acc[mt][nt] = __builtin_amdgcn_mfma_f32_16x16x32_bf16(a_h[mt], b_l[nt], acc[mt][nt], 0, 0, 0);
                    acc[mt][nt] = __builtin_amdgcn_mfma_f32_16x16x32_bf16(a_l[mt], b_h[nt], acc[mt][nt], 0, 0, 0);
                }
        }
    }

    const int crow = (lane >> 4) * 4;
    if (isQ) {
        #pragma unroll
        for (int mt = 0; mt < 2; ++mt)
            #pragma unroll
            for (int nt = 0; nt < 2; ++nt)
                #pragma unroll
                for (int i = 0; i < 4; ++i) {
                    const int m = b * 256 + q * 64 + wm + mt*16 + crow + i;
                    const int n = tileN + wn + nt*16 + r16;
                    eq[(size_t)m * DD + n] = __builtin_amdgcn_exp2f(acc[mt][nt][i] * C2LOG2E);
                }
    } else {
        __syncthreads();
        #pragma unroll
        for (int mt = 0; mt < 2; ++mt)
            #pragma unroll
            for (int nt = 0; nt < 2; ++nt)
                #pragma unroll
                for (int i = 0; i < 4; ++i)
                    Cst[(wm + mt*16 + crow + i) * 69 + wn + nt*16 + r16] =
                        __builtin_amdgcn_exp2f(acc[mt][nt][i] * C2LOG2E);
        __syncthreads();
        const int n  = tid & 63;       // local k
        const int sg = tid >> 6;       // s-quarter of the 64-row tile
        float* dstp = ekT + (size_t)b * DD * SS + (size_t)(tileN + n) * SS + q * 64 + sg * 16;
        #pragma unroll
        for (int j4 = 0; j4 < 4; ++j4) {
            float4 o;
            o.x = Cst[(sg*16 + j4*4 + 0) * 69 + n];
            o.y = Cst[(sg*16 + j4*4 + 1) * 69 + n];
            o.z = Cst[(sg*16 + j4*4 + 2) * 69 + n];
            o.w = Cst[(sg*16 + j4*4 + 3) * 69 + n];
            *(float4*)(dstp + j4 * 4) = o;
        }
    }
}

// ---------------------------------------------------------------------------
// Fused attention. 512 blocks x 1024 threads (16 waves), XCD-pinned.
// Block = (b, 4 t-rows). Wave w owns k-chunk [32w, 32w+32); lane owns
// 4 s (s = lane + 64j). eq/va are WAVE-UNIFORM: w forced uniform via
// readfirstlane so the compiler emits scalar s_load (SMEM pipe) for them —
// zero VALU/VMEM cost. ek: scalar loads, coalesced 256B/wave. 4-way
// k-batched rcp (13 VALU + 1 rcp / 4 el, vb from SGPR). wacc: 8 slots +
// paired-wave add pass (32KB). weight = -2*sum (+const dropped by softmax).
// ---------------------------------------------------------------------------
__global__ __launch_bounds__(1024, 4) void attn_fused(const float* __restrict__ eq,
                                                      const float* __restrict__ ekT,
                                                      const float* __restrict__ va,
                                                      const float* __restrict__ values,
                                                      float* __restrict__ out) {
    __shared__ __align__(16) float wacc[8][4][256];  // 32 KB [slot][t][s]
    __shared__ __align__(16) float w_s[4][256];      // 4 KB
    __shared__ float red_m[4][4];                    // [sq][t]
    __shared__ float red_s[4][4];

    const int tid  = threadIdx.x;
    const int lane = tid & 63;
    const int w    = __builtin_amdgcn_readfirstlane(tid >> 6);  // uniform wave id
    const int idx  = blockIdx.x;
    const int b    = idx & 7;           // XCD pin
    const int t0   = (idx >> 3) * 4;
    const int k0   = w * 32;            // 16 waves x 32-k chunks

    // Uniform base pointers -> scalar loads
    const float* eqb = eq + (size_t)(b * TT + t0) * DD + k0;   // 4 rows, stride DD
    const float* vap = va + k0;
    const float* ekq = ekT + ((size_t)b * DD + k0) * SS;

    float acc[4][4] = {};   // [t][j], s = lane + 64j

    #pragma unroll 2
    for (int kk = 0; kk < 32; kk += 4) {
        // wave-uniform (SGPR) operands
        float4 q0 = *(const float4*)(eqb + 0 * DD + kk);
        float4 q1 = *(const float4*)(eqb + 1 * DD + kk);
        float4 q2 = *(const float4*)(eqb + 2 * DD + kk);
        float4 q3 = *(const float4*)(eqb + 3 * DD + kk);
        float4 vb = *(const float4*)(vap + kk);
        const float* ekr = ekq + (size_t)kk * SS + lane;
        #pragma unroll
        for (int j = 0; j < 4; ++j) {
            float e0 = ekr[j * 64 + 0 * SS];
            float e1 = ekr[j * 64 + 1 * SS];
            float e2 = ekr[j * 64 + 2 * SS];
            float e3 = ekr[j * 64 + 3 * SS];
#define GS(Q, ACC) {                                                           \
        float y0 = fmaf(Q.x, e0, 1.0f);                                        \
        float y1 = fmaf(Q.y, e1, 1.0f);                                        \
        float y2 = fmaf(Q.z, e2, 1.0f);                                        \
        float y3 = fmaf(Q.w, e3, 1.0f);                                        \
        float d01 = y0 * y1, d23 = y2 * y3;                                    \
        float n01 = fmaf(vb.x, y1, vb.y * y0);                                 \
        float n23 = fmaf(vb.z, y3, vb.w * y2);                                 \
        ACC = fmaf(fmaf(n01, d23, n23 * d01),                                  \
                   __builtin_amdgcn_rcpf(d01 * d23), ACC);                     \
    }
            GS(q0, acc[0][j])
            GS(q1, acc[1][j])
            GS(q2, acc[2][j])
            GS(q3, acc[3][j])
#undef GS
        }
    }

    // Combine 16 waves into 8 slots: waves 0-7 write, 8-15 add after barrier.
    const int slot = w & 7;
    if (w < 8) {
        #pragma unroll
        for (int t = 0; t < 4; ++t)
            #pragma unroll
            for (int j = 0; j < 4; ++j)
                wacc[slot][t][lane + 64 * j] = acc[t][j];
    }
    __syncthreads();
    if (w >= 8) {
        #pragma unroll
        for (int t = 0; t < 4; ++t)
            #pragma unroll
            for (int j = 0; j < 4; ++j)
                wacc[slot][t][lane + 64 * j] += acc[t][j];
    }
    __syncthreads();

    // Softmax: wave w -> (t = w&3, sq = w>>2); lane owns s = sq*64+lane
    const int t  = w & 3;
    const int sq = w >> 2;
    const int s  = sq * 64 + lane;
    float wt = 0.f;
    #pragma unroll
    for (int cc = 0; cc < 8; ++cc) wt += wacc[cc][t][s];
    wt *= -2.0f;
    {
        float m = wt;
        #pragma unroll
        for (int off = 32; off > 0; off >>= 1) m = fmaxf(m, __shfl_xor(m, off));
        if (lane == 0) red_m[sq][t] = m;
    }
    __syncthreads();
    const float M = fmaxf(fmaxf(red_m[0][t], red_m[1][t]),
                          fmaxf(red_m[2][t], red_m[3][t]));
    float p = __builtin_amdgcn_exp2f((wt - M) * LOG2E);
    {
        float sm = p;
        #pragma unroll
        for (int off = 32; off > 0; off >>= 1) sm += __shfl_xor(sm, off);
        if (lane == 0) red_s[sq][t] = sm;
    }
    __syncthreads();
    {
        float inv = __builtin_amdgcn_rcpf((red_s[0][t] + red_s[1][t]) +
                                          (red_s[2][t] + red_s[3][t]));
        float sc = p * inv;
        out[(size_t)(b * TT + t0 + t) * SS + s] = sc;
        w_s[t][s] = sc;
    }
    __syncthreads();

    // ctx: v-column = tid&511, t-pair = tid>>9
    const int v   = tid & 511;
    const int th2 = tid >> 9;
    const float* vcol = values + (size_t)b * SS * DD + v;
    const float4* wr0 = (const float4*)&w_s[th2 * 2][0];
    const float4* wr1 = (const float4*)&w_s[th2 * 2 + 1][0];
    float c0 = 0.f, c1 = 0.f;
    #pragma unroll 4
    for (int ss = 0; ss < SS; ss += 4) {
        float4 w0 = wr0[ss >> 2];
        float4 w1 = wr1[ss >> 2];
        float v0 = vcol[(size_t)(ss + 0) * DD];
        float v1 = vcol[(size_t)(ss + 1) * DD];
        float v2 = vcol[(size_t)(ss + 2) * DD];
        float v3 = vcol[(size_t)(ss + 3) * DD];
        c0 = fmaf(w0.x, v0, c0); c1 = fmaf(w1.x, v0, c1);
        c0 = fmaf(w0.y, v1, c0); c1 = fmaf(w1.y, v1, c1);
        c0 = fmaf(w0.z, v2, c0); c1 = fmaf(w1.z, v2, c1);
        c0 = fmaf(w0.w, v3, c0); c1 = fmaf(w1.w, v3, c1);
    }
    float* octx = out + (size_t)BB * TT * SS + (size_t)(b * TT + t0 + th2 * 2) * DD + v;
    octx[0]  = c0;
    octx[DD] = c1;
}

// ---------------------------------------------------------------------------
extern "C" void kernel_launch(void* const* d_in, const int* in_sizes, int n_in,
                              void* d_out, int out_size, void* d_ws, size_t ws_size,
                              hipStream_t stream) {
    const float* query  = (const float*)d_in[0];
    const float* keys   = (const float*)d_in[1];
    const float* values = (const float*)d_in[2];
    const float* Wa     = (const float*)d_in[3];
    const float* va     = (const float*)d_in[4];
    float* out = (float*)d_out;

    float* eq  = (float*)d_ws;                    // 2048 x 512 f32 = 4 MB
    float* ekT = eq + (size_t)BB * TT * DD;       // 8 x 512 x 256 f32 = 4 MB

    gemm_mfma<<<512, 256, 0, stream>>>(query, keys, Wa, eq, ekT);
    attn_fused<<<512, 1024, 0, stream>>>(eq, ekT, va, values, out);
}

// Round 13
// 57.197 us; speedup vs baseline: 2.4543x; 1.1216x over previous
//
#include <hip/hip_runtime.h>
#include <hip/hip_bf16.h>

#define TT   256
#define BB   8
#define SS   256
#define DD   512
#define C2LOG2E 2.8853900817779268f   // 2*log2(e)
#define LOG2E   1.4426950408889634f

typedef __attribute__((ext_vector_type(8))) short bf16x8;
typedef __attribute__((ext_vector_type(4))) float f32x4;

__device__ __forceinline__ unsigned short f2bf(float f) {
    unsigned u = __builtin_bit_cast(unsigned, f);
    u += 0x7FFFu + ((u >> 16) & 1u);
    return (unsigned short)(u >> 16);
}
__device__ __forceinline__ float bf2f(unsigned short h) {
    unsigned u = (unsigned)h << 16;
    return __builtin_bit_cast(float, u);
}

// ---------------------------------------------------------------------------
// MFMA projection GEMMs, split-bf16 (hi/lo). 512 blocks, XCD-pinned.
//   z=0: eq [b*256+t][k] = exp2(c*qp)   row-major
//   z=1: ekT[b][k][s]    = exp2(c*kp)   column-major (transposed via LDS)
// ---------------------------------------------------------------------------
#define LDK 72
__global__ __launch_bounds__(256) void gemm_mfma(const float* __restrict__ query,
                                                 const float* __restrict__ keys,
                                                 const float* __restrict__ Wa,
                                                 float* __restrict__ eq,
                                                 float* __restrict__ ekT) {
    __shared__ __align__(16) unsigned char smem[4 * 64 * LDK * 2];  // 36 KB
    unsigned short* sAh = (unsigned short*)smem;
    unsigned short* sAl = sAh + 64 * LDK;
    unsigned short* sBh = sAl + 64 * LDK;
    unsigned short* sBl = sBh + 64 * LDK;
    float* Cst = (float*)smem;                // reused for z=1 transpose

    const int idx = blockIdx.x;
    const int b   = idx & 7;
    const int r2  = idx >> 3;
    const int q   = r2 & 3;
    const int x   = (r2 >> 2) & 7;
    const int z   = r2 >> 5;
    const bool isQ = (z == 0);

    const float* A  = isQ ? query : keys;
    const int strideR = isQ ? BB * DD : DD;
    const int strideB = isQ ? DD : SS * DD;
    const float* Bsrc = Wa + (isQ ? 0 : DD);

    const int tileN = x * 64;
    const int tid = threadIdx.x;
    const int rb  = tid >> 4;
    const int c4  = tid & 15;

    const float* arow0 = A + (size_t)b * strideB + (size_t)(q * 64) * strideR;
    const float* brow0 = Bsrc + (size_t)tileN * (2 * DD);

    float4 av[4], bv[4];
    #pragma unroll
    for (int i = 0; i < 4; ++i) {
        av[i] = *(const float4*)(arow0 + (size_t)(rb + 16*i) * strideR + c4 * 4);
        bv[i] = *(const float4*)(brow0 + (size_t)(rb + 16*i) * (2*DD) + c4 * 4);
    }

    const int w    = tid >> 6;
    const int lane = tid & 63;
    const int wm   = (w >> 1) * 32;
    const int wn   = (w & 1) * 32;
    const int r16  = lane & 15;
    const int k8   = (lane >> 4) * 8;

    f32x4 acc[2][2] = {};

    for (int kb = 0; kb < DD; kb += 64) {
        __syncthreads();
        #pragma unroll
        for (int i = 0; i < 4; ++i) {
            const int row = rb + 16 * i;
            float4 a = av[i], bq = bv[i];
            ushort4 ah, al, bh, bl;
            ah.x = f2bf(a.x); al.x = f2bf(a.x - bf2f(ah.x));
            ah.y = f2bf(a.y); al.y = f2bf(a.y - bf2f(ah.y));
            ah.z = f2bf(a.z); al.z = f2bf(a.z - bf2f(ah.z));
            ah.w = f2bf(a.w); al.w = f2bf(a.w - bf2f(ah.w));
            bh.x = f2bf(bq.x); bl.x = f2bf(bq.x - bf2f(bh.x));
            bh.y = f2bf(bq.y); bl.y = f2bf(bq.y - bf2f(bh.y));
            bh.z = f2bf(bq.z); bl.z = f2bf(bq.z - bf2f(bh.z));
            bh.w = f2bf(bq.w); bl.w = f2bf(bq.w - bf2f(bh.w));
            *(ushort4*)(sAh + row * LDK + c4 * 4) = ah;
            *(ushort4*)(sAl + row * LDK + c4 * 4) = al;
            *(ushort4*)(sBh + row * LDK + c4 * 4) = bh;
            *(ushort4*)(sBl + row * LDK + c4 * 4) = bl;
        }
        __syncthreads();
        if (kb + 64 < DD) {
            #pragma unroll
            for (int i = 0; i < 4; ++i) {
                av[i] = *(const float4*)(arow0 + (size_t)(rb + 16*i) * strideR + kb + 64 + c4 * 4);
                bv[i] = *(const float4*)(brow0 + (size_t)(rb + 16*i) * (2*DD) + kb + 64 + c4 * 4);
            }
        }
        #pragma unroll
        for (int ks = 0; ks < 2; ++ks) {
            const int ko = ks * 32 + k8;
            bf16x8 a_h[2], a_l[2], b_h[2], b_l[2];
            #pragma unroll
            for (int mt = 0; mt < 2; ++mt) {
                a_h[mt] = *(const bf16x8*)(sAh + (wm + mt*16 + r16) * LDK + ko);
                a_l[mt] = *(const bf16x8*)(sAl + (wm + mt*16 + r16) * LDK + ko);
            }
            #pragma unroll
            for (int nt = 0; nt < 2; ++nt) {
                b_h[nt] = *(const bf16x8*)(sBh + (wn + nt*16 + r16) * LDK + ko);
                b_l[nt] = *(const bf16x8*)(sBl + (wn + nt*16 + r16) * LDK + ko);
            }
            #pragma unroll
            for (int mt = 0; mt < 2; ++mt)
                #pragma unroll
                for (int nt = 0; nt < 2; ++nt) {
                    acc[mt][nt] = __builtin_amdgcn_mfma_f32_16x16x32_bf16(a_h[mt], b_h[nt], acc[mt][nt], 0, 0, 0);
                    acc[mt][nt] = __builtin_amdgcn_mfma_f32_16x16x32_bf16(a_h[mt], b_l[nt], acc[mt][nt], 0, 0, 0);
                    acc[mt][nt] = __builtin_amdgcn_mfma_f32_16x16x32_bf16(a_l[mt], b_h[nt], acc[mt][nt], 0, 0, 0);
                }
        }
    }

    const int crow = (lane >> 4) * 4;
    if (isQ) {
        #pragma unroll
        for (int mt = 0; mt < 2; ++mt)
            #pragma unroll
            for (int nt = 0; nt < 2; ++nt)
                #pragma unroll
                for (int i = 0; i < 4; ++i) {
                    const int m = b * 256 + q * 64 + wm + mt*16 + crow + i;
                    const int n = tileN + wn + nt*16 + r16;
                    eq[(size_t)m * DD + n] = __builtin_amdgcn_exp2f(acc[mt][nt][i] * C2LOG2E);
                }
    } else {
        __syncthreads();
        #pragma unroll
        for (int mt = 0; mt < 2; ++mt)
            #pragma unroll
            for (int nt = 0; nt < 2; ++nt)
                #pragma unroll
                for (int i = 0; i < 4; ++i)
                    Cst[(wm + mt*16 + crow + i) * 69 + wn + nt*16 + r16] =
                        __builtin_amdgcn_exp2f(acc[mt][nt][i] * C2LOG2E);
        __syncthreads();
        const int n  = tid & 63;       // local k
        const int sg = tid >> 6;       // s-quarter of the 64-row tile
        float* dstp = ekT + (size_t)b * DD * SS + (size_t)(tileN + n) * SS + q * 64 + sg * 16;
        #pragma unroll
        for (int j4 = 0; j4 < 4; ++j4) {
            float4 o;
            o.x = Cst[(sg*16 + j4*4 + 0) * 69 + n];
            o.y = Cst[(sg*16 + j4*4 + 1) * 69 + n];
            o.z = Cst[(sg*16 + j4*4 + 2) * 69 + n];
            o.w = Cst[(sg*16 + j4*4 + 3) * 69 + n];
            *(float4*)(dstp + j4 * 4) = o;
        }
    }
}

// ---------------------------------------------------------------------------
// Fused attention. 256 blocks x 1024 threads (16 waves), XCD-pinned, exactly
// 1 block/CU. Block = (b, 8 t-rows). Wave w owns k-chunk [32w, 32w+32);
// lane owns 4 s (s = lane + 64j). Each ek load feeds 8 GS (8 t-rows) —
// half the VMEM rate of the 4-t design. eq/va are wave-uniform -> scalar
// s_load (SMEM pipe). 4-way k-batched rcp (13 VALU + 1 rcp / 4 el).
// wacc: 8 slots + paired-wave add (64 KB). weight = -2*sum (+const dropped).
// ---------------------------------------------------------------------------
__global__ __launch_bounds__(1024, 4) void attn_fused(const float* __restrict__ eq,
                                                      const float* __restrict__ ekT,
                                                      const float* __restrict__ va,
                                                      const float* __restrict__ values,
                                                      float* __restrict__ out) {
    __shared__ __align__(16) float wacc[8][8][256];  // 64 KB [slot][t][s]
    __shared__ __align__(16) float w_s[8][256];      // 8 KB
    __shared__ float red_m[4][8];                    // [sq][t]
    __shared__ float red_s[4][8];

    const int tid  = threadIdx.x;
    const int lane = tid & 63;
    const int w    = __builtin_amdgcn_readfirstlane(tid >> 6);  // uniform wave id
    const int idx  = blockIdx.x;        // 256 blocks
    const int b    = idx & 7;           // XCD pin
    const int t0   = (idx >> 3) * 8;    // 8 t-rows per block
    const int k0   = w * 32;            // 16 waves x 32-k chunks

    // Uniform base pointers -> scalar loads
    const float* eqb = eq + (size_t)(b * TT + t0) * DD + k0;   // 8 rows, stride DD
    const float* vap = va + k0;
    const float* ekq = ekT + ((size_t)b * DD + k0) * SS;

    float acc[8][4] = {};   // [t][j], s = lane + 64j

    #pragma unroll 2
    for (int kk = 0; kk < 32; kk += 4) {
        // wave-uniform (SGPR) operands: 8 q-rows + vb
        float4 q0 = *(const float4*)(eqb + 0 * DD + kk);
        float4 q1 = *(const float4*)(eqb + 1 * DD + kk);
        float4 q2 = *(const float4*)(eqb + 2 * DD + kk);
        float4 q3 = *(const float4*)(eqb + 3 * DD + kk);
        float4 q4 = *(const float4*)(eqb + 4 * DD + kk);
        float4 q5 = *(const float4*)(eqb + 5 * DD + kk);
        float4 q6 = *(const float4*)(eqb + 6 * DD + kk);
        float4 q7 = *(const float4*)(eqb + 7 * DD + kk);
        float4 vb = *(const float4*)(vap + kk);
        const float* ekr = ekq + (size_t)kk * SS + lane;
        #pragma unroll
        for (int j = 0; j < 4; ++j) {
            float e0 = ekr[j * 64 + 0 * SS];
            float e1 = ekr[j * 64 + 1 * SS];
            float e2 = ekr[j * 64 + 2 * SS];
            float e3 = ekr[j * 64 + 3 * SS];
#define GS(Q, ACC) {                                                           \
        float y0 = fmaf(Q.x, e0, 1.0f);                                        \
        float y1 = fmaf(Q.y, e1, 1.0f);                                        \
        float y2 = fmaf(Q.z, e2, 1.0f);                                        \
        float y3 = fmaf(Q.w, e3, 1.0f);                                        \
        float d01 = y0 * y1, d23 = y2 * y3;                                    \
        float n01 = fmaf(vb.x, y1, vb.y * y0);                                 \
        float n23 = fmaf(vb.z, y3, vb.w * y2);                                 \
        ACC = fmaf(fmaf(n01, d23, n23 * d01),                                  \
                   __builtin_amdgcn_rcpf(d01 * d23), ACC);                     \
    }
            GS(q0, acc[0][j])
            GS(q1, acc[1][j])
            GS(q2, acc[2][j])
            GS(q3, acc[3][j])
            GS(q4, acc[4][j])
            GS(q5, acc[5][j])
            GS(q6, acc[6][j])
            GS(q7, acc[7][j])
#undef GS
        }
    }

    // Combine 16 waves into 8 slots: waves 0-7 write, 8-15 add after barrier.
    const int slot = w & 7;
    if (w < 8) {
        #pragma unroll
        for (int t = 0; t < 8; ++t)
            #pragma unroll
            for (int j = 0; j < 4; ++j)
                wacc[slot][t][lane + 64 * j] = acc[t][j];
    }
    __syncthreads();
    if (w >= 8) {
        #pragma unroll
        for (int t = 0; t < 8; ++t)
            #pragma unroll
            for (int j = 0; j < 4; ++j)
                wacc[slot][t][lane + 64 * j] += acc[t][j];
    }
    __syncthreads();

    // Softmax: wave w -> t = w&7, s-half = w>>3 (two sq slices each)
    const int t   = w & 7;
    const int sh2 = w >> 3;           // 0 or 1
    float wt[2], p[2];
    #pragma unroll
    for (int u = 0; u < 2; ++u) {
        const int s = (sh2 * 2 + u) * 64 + lane;
        float acc_s = 0.f;
        #pragma unroll
        for (int cc = 0; cc < 8; ++cc) acc_s += wacc[cc][t][s];
        wt[u] = acc_s * -2.0f;
        float m = wt[u];
        #pragma unroll
        for (int off = 32; off > 0; off >>= 1) m = fmaxf(m, __shfl_xor(m, off));
        if (lane == 0) red_m[sh2 * 2 + u][t] = m;
    }
    __syncthreads();
    const float M = fmaxf(fmaxf(red_m[0][t], red_m[1][t]),
                          fmaxf(red_m[2][t], red_m[3][t]));
    #pragma unroll
    for (int u = 0; u < 2; ++u) {
        p[u] = __builtin_amdgcn_exp2f((wt[u] - M) * LOG2E);
        float sm = p[u];
        #pragma unroll
        for (int off = 32; off > 0; off >>= 1) sm += __shfl_xor(sm, off);
        if (lane == 0) red_s[sh2 * 2 + u][t] = sm;
    }
    __syncthreads();
    {
        float inv = __builtin_amdgcn_rcpf((red_s[0][t] + red_s[1][t]) +
                                          (red_s[2][t] + red_s[3][t]));
        #pragma unroll
        for (int u = 0; u < 2; ++u) {
            const int s = (sh2 * 2 + u) * 64 + lane;
            float sc = p[u] * inv;
            out[(size_t)(b * TT + t0 + t) * SS + s] = sc;
            w_s[t][s] = sc;
        }
    }
    __syncthreads();

    // ctx: v-column = tid&511, t-group of 4 = tid>>9
    const int v  = tid & 511;
    const int tg = (tid >> 9) * 4;
    const float* vcol = values + (size_t)b * SS * DD + v;
    const float4* wr0 = (const float4*)&w_s[tg + 0][0];
    const float4* wr1 = (const float4*)&w_s[tg + 1][0];
    const float4* wr2 = (const float4*)&w_s[tg + 2][0];
    const float4* wr3 = (const float4*)&w_s[tg + 3][0];
    float c0 = 0.f, c1 = 0.f, c2 = 0.f, c3 = 0.f;
    #pragma unroll 4
    for (int ss = 0; ss < SS; ss += 4) {
        float4 w0 = wr0[ss >> 2];
        float4 w1 = wr1[ss >> 2];
        float4 w2 = wr2[ss >> 2];
        float4 w3 = wr3[ss >> 2];
        float v0 = vcol[(size_t)(ss + 0) * DD];
        float v1 = vcol[(size_t)(ss + 1) * DD];
        float v2 = vcol[(size_t)(ss + 2) * DD];
        float v3 = vcol[(size_t)(ss + 3) * DD];
        c0 = fmaf(w0.x, v0, c0); c1 = fmaf(w1.x, v0, c1);
        c2 = fmaf(w2.x, v0, c2); c3 = fmaf(w3.x, v0, c3);
        c0 = fmaf(w0.y, v1, c0); c1 = fmaf(w1.y, v1, c1);
        c2 = fmaf(w2.y, v1, c2); c3 = fmaf(w3.y, v1, c3);
        c0 = fmaf(w0.z, v2, c0); c1 = fmaf(w1.z, v2, c1);
        c2 = fmaf(w2.z, v2, c2); c3 = fmaf(w3.z, v2, c3);
        c0 = fmaf(w0.w, v3, c0); c1 = fmaf(w1.w, v3, c1);
        c2 = fmaf(w2.w, v3, c2); c3 = fmaf(w3.w, v3, c3);
    }
    float* octx = out + (size_t)BB * TT * SS + (size_t)(b * TT + t0 + tg) * DD + v;
    octx[0 * DD] = c0; octx[1 * DD] = c1;
    octx[2 * DD] = c2; octx[3 * DD] = c3;
}

// ---------------------------------------------------------------------------
extern "C" void kernel_launch(void* const* d_in, const int* in_sizes, int n_in,
                              void* d_out, int out_size, void* d_ws, size_t ws_size,
                              hipStream_t stream) {
    const float* query  = (const float*)d_in[0];
    const float* keys   = (const float*)d_in[1];
    const float* values = (const float*)d_in[2];
    const float* Wa     = (const float*)d_in[3];
    const float* va     = (const float*)d_in[4];
    float* out = (float*)d_out;

    float* eq  = (float*)d_ws;                    // 2048 x 512 f32 = 4 MB
    float* ekT = eq + (size_t)BB * TT * DD;       // 8 x 512 x 256 f32 = 4 MB

    gemm_mfma<<<512, 256, 0, stream>>>(query, keys, Wa, eq, ekT);
    attn_fused<<<256, 1024, 0, stream>>>(eq, ekT, va, values, out);
}